// Round 8
// baseline (168.801 us; speedup 1.0000x reference)
//
#include <hip/hip_runtime.h>

#define IMG_W 512
#define IMG_H 512
#define BATCH 64
#define STRIP_ROWS 8
#define STRIPS_PER_IMG (IMG_H / STRIP_ROWS)        // 64
#define NSTRIPS (BATCH * STRIPS_PER_IMG)           // 4096 strips, 1 per wave
#define NB_MAIN (NSTRIPS / 4)                      // 1024 blocks x 4 waves
#define NPIX (BATCH * IMG_W * IMG_H)

typedef float f32x4 __attribute__((ext_vector_type(4)));

__device__ __forceinline__ float fast_sqrtf(float x) {
    return __builtin_amdgcn_sqrtf(x);
}

// R16: occupancy, the never-moved lever. R7's plain-HIP probe: 37MB in
// ~6.4us = 5.8 TB/s (8.7 B/cyc/CU) with 4 waves/CU -> the access pattern
// delivers near-ceiling; T-A confirmed. All prior structures launched only
// 2048 waves = 8 waves/CU (grid-limited occupancy 16-23%, NOT VGPR-limited:
// 76 VGPR allows ~24/CU). Each wave alternates {wait, ~170cyc compute}; 8
// waves can't fill the gaps -> both pipes starve (VALU 21%, mem ~55% duty).
// Fix: 8-row strips -> 4096 waves = 16 waves/CU. Traffic 147->168MB (+14%,
// halo amplification, L3-absorbed). Schedule = R12's proven 6-slot ring,
// lookahead 3, steady vmcnt(6/6), re-ledgered tails: r=6:(6,4), r=7:(2,0).

#define GLOAD(dst, ptr)                                                        \
    asm volatile("global_load_dwordx4 %0, %1, off" : "=v"(dst) : "v"(ptr))

// rolling-buffer slots (k is a compile-time row index, -1..8)
#define S6(k) (((k) + 1) % 6)
#define S3(k) (((k) + 1) % 3)

// window element j (0..9) of row k: 0 = left halo, 9 = right halo
#define WEL(A, B, HL, HR, k, j)                                                \
    ((j) == 0 ? HL[S3(k)]                                                      \
              : ((j) == 9 ? HR[S3(k)]                                          \
                          : ((j) <= 4 ? A[S6(k)][(j) - 1] : B[S6(k)][(j) - 5])))

// issue the 2 dwordx4 loads of row k (y-clamped; halo rows zeroed post-wait)
#define ISSUE(k, A, B, IMG)                                                    \
    {                                                                          \
        int gy_ = stripy + (k);                                                \
        gy_ = gy_ < 0 ? 0 : (gy_ > IMG_H - 1 ? IMG_H - 1 : gy_);               \
        const float* r_ = (IMG) + ((size_t)gy_ << 9) + x0;                     \
        GLOAD(A[S6(k)], r_);                                                   \
        GLOAD(B[S6(k)], r_ + 4);                                               \
    }

// after row k's data is present: build halo floats + horizontal 1-2-1 sums
#define PREP(k, A, B, HL, HR, HS)                                              \
    {                                                                          \
        float l_ = __shfl_up(B[S6(k)][3], 1, 64);                              \
        float r_ = __shfl_down(A[S6(k)][0], 1, 64);                            \
        HL[S3(k)] = (lane == 0) ? 0.f : l_;                                    \
        HR[S3(k)] = (lane == 63) ? 0.f : r_;                                   \
        _Pragma("unroll")                                                      \
        for (int j = 0; j < 8; ++j)                                            \
            HS[S3(k)][j] = fmaf(2.f, WEL(A, B, HL, HR, k, j + 1),              \
                                WEL(A, B, HL, HR, k, j)) +                     \
                           WEL(A, B, HL, HR, k, j + 2);                        \
    }

// output row r of image p: store magnitudes into magrow
#define OUT_P(r)                                                               \
    {                                                                          \
        float c9_[10];                                                         \
        _Pragma("unroll")                                                      \
        for (int j = 0; j < 10; ++j)                                           \
            c9_[j] = fmaf(2.f, WEL(pA, pB, hlP, hrP, (r), j),                  \
                          WEL(pA, pB, hlP, hrP, (r)-1, j)) +                   \
                     WEL(pA, pB, hlP, hrP, (r) + 1, j);                        \
        _Pragma("unroll")                                                      \
        for (int j = 0; j < 8; ++j) {                                          \
            float gh = hsP[S3((r) + 1)][j] - hsP[S3((r)-1)][j];                \
            float gv = c9_[j + 2] - c9_[j];                                    \
            magrow[j] = fast_sqrtf(fmaf(gv, gv, fmaf(gh, gh, 1e-18f)));        \
        }                                                                      \
    }

// output row r of image t: fused |magt - magp| accumulation
#define OUT_T(r)                                                               \
    {                                                                          \
        float c9_[10];                                                         \
        _Pragma("unroll")                                                      \
        for (int j = 0; j < 10; ++j)                                           \
            c9_[j] = fmaf(2.f, WEL(tA, tB, hlT, hrT, (r), j),                  \
                          WEL(tA, tB, hlT, hrT, (r)-1, j)) +                   \
                     WEL(tA, tB, hlT, hrT, (r) + 1, j);                        \
        _Pragma("unroll")                                                      \
        for (int j = 0; j < 8; ++j) {                                          \
            float gh = hsT[S3((r) + 1)][j] - hsT[S3((r)-1)][j];                \
            float gv = c9_[j + 2] - c9_[j];                                    \
            float mt = fast_sqrtf(fmaf(gv, gv, fmaf(gh, gh, 1e-18f)));         \
            lsum += fabsf(mt - magrow[j]); /* == sqrt(d^2+eps)*(d^2!=0) */     \
        }                                                                      \
    }

// One output row (R12 schedule, 8-row strip). Queue simulation:
// prologue leaves [p-1,t-1,p0,t0,p1,t1,p2,t2] (16 insts).
// wait-p(r) needs p_{r+1}: remaining [t_{r+1},p_{r+2},t_{r+2}] = 6 insts.
// wait-t(r) needs t_{r+1}: remaining [p_{r+2},t_{r+2},p_{r+3}] = 6 insts.
// Issues while r+3 <= 8 (r <= 5). Tails: r=6:(6,4), r=7:(2,0).
// sched_barrier after each wait: rule #18.
#define ITER(r, WP, WT)                                                        \
    {                                                                          \
        float magrow[8];                                                       \
        asm volatile("s_waitcnt vmcnt(" #WP ")" ::: "memory");                 \
        __builtin_amdgcn_sched_barrier(0);                                     \
        if ((r) == 0 && stop_) { pA[S6(-1)] = z4; pB[S6(-1)] = z4; }           \
        if ((r) == 7 && sbot_) { pA[S6(8)] = z4; pB[S6(8)] = z4; }             \
        if ((r) == 0) {                                                        \
            PREP(-1, pA, pB, hlP, hrP, hsP)                                    \
            PREP(0, pA, pB, hlP, hrP, hsP)                                     \
        }                                                                      \
        PREP((r) + 1, pA, pB, hlP, hrP, hsP)                                   \
        if ((r) <= 5) ISSUE((r) + 3, pA, pB, imgp)                             \
        OUT_P(r)                                                               \
        asm volatile("s_waitcnt vmcnt(" #WT ")" ::: "memory");                 \
        __builtin_amdgcn_sched_barrier(0);                                     \
        if ((r) == 0 && stop_) { tA[S6(-1)] = z4; tB[S6(-1)] = z4; }           \
        if ((r) == 7 && sbot_) { tA[S6(8)] = z4; tB[S6(8)] = z4; }             \
        if ((r) == 0) {                                                        \
            PREP(-1, tA, tB, hlT, hrT, hsT)                                    \
            PREP(0, tA, tB, hlT, hrT, hsT)                                     \
        }                                                                      \
        PREP((r) + 1, tA, tB, hlT, hrT, hsT)                                   \
        if ((r) <= 5) ISSUE((r) + 3, tA, tB, imgt)                             \
        OUT_T(r)                                                               \
    }

__global__ __launch_bounds__(256, 4) void sobel_loss_kernel(
    const float* __restrict__ yp, const float* __restrict__ yt,
    float* __restrict__ bsums)
{
    __shared__ float wred[4];

    const int tid  = threadIdx.x;
    const int lane = tid & 63;
    const int w    = tid >> 6;                  // wave id 0..3

    const int bid    = blockIdx.x;
    const int strip  = (bid << 2) + w;          // strip 0..4095
    const int b      = strip >> 6;              // image (64 strips/image)
    const int srow   = strip & 63;              // strip row-index in image
    const int stripy = srow << 3;               // first output row
    const int x0     = lane << 3;               // cols x0..x0+7

    const bool stop_ = (srow == 0);
    const bool sbot_ = (srow == STRIPS_PER_IMG - 1);

    const float* imgp = yp + ((size_t)b << 18);
    const float* imgt = yt + ((size_t)b << 18);

    // rolling register state: row k -> slot S6(k); halo/HS -> slot S3(k)
    f32x4 pA[6], pB[6], tA[6], tB[6];
    float hlP[3], hrP[3], hlT[3], hrT[3];
    float hsP[3][8], hsT[3][8];

    const f32x4 z4 = {0.f, 0.f, 0.f, 0.f};
    float lsum = 0.f;

    // ---- prologue: rows -1..2, both images, interleaved p,t ----
    ISSUE(-1, pA, pB, imgp) ISSUE(-1, tA, tB, imgt)
    ISSUE(0,  pA, pB, imgp) ISSUE(0,  tA, tB, imgt)
    ISSUE(1,  pA, pB, imgp) ISSUE(1,  tA, tB, imgt)
    ISSUE(2,  pA, pB, imgp) ISSUE(2,  tA, tB, imgt)

    // ---- 8 output rows, steady waits vmcnt(6/6), tails (6,4), (2,0) ----
    ITER(0, 6, 6)  ITER(1, 6, 6)  ITER(2, 6, 6)  ITER(3, 6, 6)
    ITER(4, 6, 6)  ITER(5, 6, 6)  ITER(6, 6, 4)  ITER(7, 2, 0)

    // ---- Block reduction ----
#pragma unroll
    for (int off = 32; off > 0; off >>= 1)
        lsum += __shfl_down(lsum, off, 64);
    if (lane == 0) wred[w] = lsum;
    __syncthreads();
    if (tid == 0)
        bsums[bid] = wred[0] + wred[1] + wred[2] + wred[3];
}

__global__ __launch_bounds__(256) void reduce_final(
    const float* __restrict__ bsums, float* __restrict__ out)
{
    __shared__ float wred[4];
    const int tid = threadIdx.x;
    float s = 0.f;
    for (int i = tid; i < NB_MAIN; i += 256) s += bsums[i];
#pragma unroll
    for (int off = 32; off > 0; off >>= 1)
        s += __shfl_down(s, off, 64);
    if ((tid & 63) == 0) wred[tid >> 6] = s;
    __syncthreads();
    if (tid == 0)
        out[0] = (wred[0] + wred[1] + wred[2] + wred[3]) * (1.0f / (float)NPIX);
}

extern "C" void kernel_launch(void* const* d_in, const int* in_sizes, int n_in,
                              void* d_out, int out_size, void* d_ws, size_t ws_size,
                              hipStream_t stream) {
    const float* yp = (const float*)d_in[0];
    const float* yt = (const float*)d_in[1];
    float* out = (float*)d_out;

    float* bsums = (float*)d_ws;   // 4 KB of workspace
    sobel_loss_kernel<<<NB_MAIN, 256, 0, stream>>>(yp, yt, bsums);
    reduce_final<<<1, 256, 0, stream>>>(bsums, out);
}

// Round 9
// 146.474 us; speedup vs baseline: 1.1524x; 1.1524x over previous
//
#include <hip/hip_runtime.h>

#define IMG_W 512
#define IMG_H 512
#define BATCH 64
#define STRIP_ROWS 8
#define STRIPS_PER_IMG (IMG_H / STRIP_ROWS)        // 64
#define NSTRIPS (BATCH * STRIPS_PER_IMG)           // 4096 strips, 1 per wave
#define NB_MAIN (NSTRIPS / 4)                      // 1024 blocks x 4 waves
#define NPIX (BATCH * IMG_W * IMG_H)

typedef float f32x4 __attribute__((ext_vector_type(4)));

__device__ __forceinline__ float fast_sqrtf(float x) {
    return __builtin_amdgcn_sqrtf(x);
}

// R17: R16 minus the spill confound. R16's launch_bounds(256,4) forced the
// allocator to 64 VGPR -> ~40 dwords/lane scratch spill (WRITE_SIZE 0.06 ->
// 43.9 MB, the smoking gun), dur 70us, VALUBusy 14%. That invalidated the
// TLP test. R17: plain __launch_bounds__(256) (R12's natural allocation is
// 76 VGPR = 6 waves/SIMD possible; grid supplies 4/SIMD, no cap needed).
// Everything else = R16: 8-row strips, 4096 waves = 16 waves/CU (2x R12's
// TLP), R12's proven 6-slot ring, lookahead 3, steady vmcnt(6/6),
// tails r=6:(6,4), r=7:(2,0). Clean A/B: R17-vs-R12 isolates strip height.

#define GLOAD(dst, ptr)                                                        \
    asm volatile("global_load_dwordx4 %0, %1, off" : "=v"(dst) : "v"(ptr))

// rolling-buffer slots (k is a compile-time row index, -1..8)
#define S6(k) (((k) + 1) % 6)
#define S3(k) (((k) + 1) % 3)

// window element j (0..9) of row k: 0 = left halo, 9 = right halo
#define WEL(A, B, HL, HR, k, j)                                                \
    ((j) == 0 ? HL[S3(k)]                                                      \
              : ((j) == 9 ? HR[S3(k)]                                          \
                          : ((j) <= 4 ? A[S6(k)][(j) - 1] : B[S6(k)][(j) - 5])))

// issue the 2 dwordx4 loads of row k (y-clamped; halo rows zeroed post-wait)
#define ISSUE(k, A, B, IMG)                                                    \
    {                                                                          \
        int gy_ = stripy + (k);                                                \
        gy_ = gy_ < 0 ? 0 : (gy_ > IMG_H - 1 ? IMG_H - 1 : gy_);               \
        const float* r_ = (IMG) + ((size_t)gy_ << 9) + x0;                     \
        GLOAD(A[S6(k)], r_);                                                   \
        GLOAD(B[S6(k)], r_ + 4);                                               \
    }

// after row k's data is present: build halo floats + horizontal 1-2-1 sums
#define PREP(k, A, B, HL, HR, HS)                                              \
    {                                                                          \
        float l_ = __shfl_up(B[S6(k)][3], 1, 64);                              \
        float r_ = __shfl_down(A[S6(k)][0], 1, 64);                            \
        HL[S3(k)] = (lane == 0) ? 0.f : l_;                                    \
        HR[S3(k)] = (lane == 63) ? 0.f : r_;                                   \
        _Pragma("unroll")                                                      \
        for (int j = 0; j < 8; ++j)                                            \
            HS[S3(k)][j] = fmaf(2.f, WEL(A, B, HL, HR, k, j + 1),              \
                                WEL(A, B, HL, HR, k, j)) +                     \
                           WEL(A, B, HL, HR, k, j + 2);                        \
    }

// output row r of image p: store magnitudes into magrow
#define OUT_P(r)                                                               \
    {                                                                          \
        float c9_[10];                                                         \
        _Pragma("unroll")                                                      \
        for (int j = 0; j < 10; ++j)                                           \
            c9_[j] = fmaf(2.f, WEL(pA, pB, hlP, hrP, (r), j),                  \
                          WEL(pA, pB, hlP, hrP, (r)-1, j)) +                   \
                     WEL(pA, pB, hlP, hrP, (r) + 1, j);                        \
        _Pragma("unroll")                                                      \
        for (int j = 0; j < 8; ++j) {                                          \
            float gh = hsP[S3((r) + 1)][j] - hsP[S3((r)-1)][j];                \
            float gv = c9_[j + 2] - c9_[j];                                    \
            magrow[j] = fast_sqrtf(fmaf(gv, gv, fmaf(gh, gh, 1e-18f)));        \
        }                                                                      \
    }

// output row r of image t: fused |magt - magp| accumulation
#define OUT_T(r)                                                               \
    {                                                                          \
        float c9_[10];                                                         \
        _Pragma("unroll")                                                      \
        for (int j = 0; j < 10; ++j)                                           \
            c9_[j] = fmaf(2.f, WEL(tA, tB, hlT, hrT, (r), j),                  \
                          WEL(tA, tB, hlT, hrT, (r)-1, j)) +                   \
                     WEL(tA, tB, hlT, hrT, (r) + 1, j);                        \
        _Pragma("unroll")                                                      \
        for (int j = 0; j < 8; ++j) {                                          \
            float gh = hsT[S3((r) + 1)][j] - hsT[S3((r)-1)][j];                \
            float gv = c9_[j + 2] - c9_[j];                                    \
            float mt = fast_sqrtf(fmaf(gv, gv, fmaf(gh, gh, 1e-18f)));         \
            lsum += fabsf(mt - magrow[j]); /* == sqrt(d^2+eps)*(d^2!=0) */     \
        }                                                                      \
    }

// One output row (R12 schedule, 8-row strip). Queue simulation:
// prologue leaves [p-1,t-1,p0,t0,p1,t1,p2,t2] (16 insts).
// wait-p(r) needs p_{r+1}: remaining [t_{r+1},p_{r+2},t_{r+2}] = 6 insts.
// wait-t(r) needs t_{r+1}: remaining [p_{r+2},t_{r+2},p_{r+3}] = 6 insts.
// Issues while r+3 <= 8 (r <= 5). Tails: r=6:(6,4), r=7:(2,0).
// sched_barrier after each wait: rule #18.
#define ITER(r, WP, WT)                                                        \
    {                                                                          \
        float magrow[8];                                                       \
        asm volatile("s_waitcnt vmcnt(" #WP ")" ::: "memory");                 \
        __builtin_amdgcn_sched_barrier(0);                                     \
        if ((r) == 0 && stop_) { pA[S6(-1)] = z4; pB[S6(-1)] = z4; }           \
        if ((r) == 7 && sbot_) { pA[S6(8)] = z4; pB[S6(8)] = z4; }             \
        if ((r) == 0) {                                                        \
            PREP(-1, pA, pB, hlP, hrP, hsP)                                    \
            PREP(0, pA, pB, hlP, hrP, hsP)                                     \
        }                                                                      \
        PREP((r) + 1, pA, pB, hlP, hrP, hsP)                                   \
        if ((r) <= 5) ISSUE((r) + 3, pA, pB, imgp)                             \
        OUT_P(r)                                                               \
        asm volatile("s_waitcnt vmcnt(" #WT ")" ::: "memory");                 \
        __builtin_amdgcn_sched_barrier(0);                                     \
        if ((r) == 0 && stop_) { tA[S6(-1)] = z4; tB[S6(-1)] = z4; }           \
        if ((r) == 7 && sbot_) { tA[S6(8)] = z4; tB[S6(8)] = z4; }             \
        if ((r) == 0) {                                                        \
            PREP(-1, tA, tB, hlT, hrT, hsT)                                    \
            PREP(0, tA, tB, hlT, hrT, hsT)                                     \
        }                                                                      \
        PREP((r) + 1, tA, tB, hlT, hrT, hsT)                                   \
        if ((r) <= 5) ISSUE((r) + 3, tA, tB, imgt)                             \
        OUT_T(r)                                                               \
    }

__global__ __launch_bounds__(256) void sobel_loss_kernel(
    const float* __restrict__ yp, const float* __restrict__ yt,
    float* __restrict__ bsums)
{
    __shared__ float wred[4];

    const int tid  = threadIdx.x;
    const int lane = tid & 63;
    const int w    = tid >> 6;                  // wave id 0..3

    const int bid    = blockIdx.x;
    const int strip  = (bid << 2) + w;          // strip 0..4095
    const int b      = strip >> 6;              // image (64 strips/image)
    const int srow   = strip & 63;              // strip row-index in image
    const int stripy = srow << 3;               // first output row
    const int x0     = lane << 3;               // cols x0..x0+7

    const bool stop_ = (srow == 0);
    const bool sbot_ = (srow == STRIPS_PER_IMG - 1);

    const float* imgp = yp + ((size_t)b << 18);
    const float* imgt = yt + ((size_t)b << 18);

    // rolling register state: row k -> slot S6(k); halo/HS -> slot S3(k)
    f32x4 pA[6], pB[6], tA[6], tB[6];
    float hlP[3], hrP[3], hlT[3], hrT[3];
    float hsP[3][8], hsT[3][8];

    const f32x4 z4 = {0.f, 0.f, 0.f, 0.f};
    float lsum = 0.f;

    // ---- prologue: rows -1..2, both images, interleaved p,t ----
    ISSUE(-1, pA, pB, imgp) ISSUE(-1, tA, tB, imgt)
    ISSUE(0,  pA, pB, imgp) ISSUE(0,  tA, tB, imgt)
    ISSUE(1,  pA, pB, imgp) ISSUE(1,  tA, tB, imgt)
    ISSUE(2,  pA, pB, imgp) ISSUE(2,  tA, tB, imgt)

    // ---- 8 output rows, steady waits vmcnt(6/6), tails (6,4), (2,0) ----
    ITER(0, 6, 6)  ITER(1, 6, 6)  ITER(2, 6, 6)  ITER(3, 6, 6)
    ITER(4, 6, 6)  ITER(5, 6, 6)  ITER(6, 6, 4)  ITER(7, 2, 0)

    // ---- Block reduction ----
#pragma unroll
    for (int off = 32; off > 0; off >>= 1)
        lsum += __shfl_down(lsum, off, 64);
    if (lane == 0) wred[w] = lsum;
    __syncthreads();
    if (tid == 0)
        bsums[bid] = wred[0] + wred[1] + wred[2] + wred[3];
}

__global__ __launch_bounds__(256) void reduce_final(
    const float* __restrict__ bsums, float* __restrict__ out)
{
    __shared__ float wred[4];
    const int tid = threadIdx.x;
    float s = 0.f;
    for (int i = tid; i < NB_MAIN; i += 256) s += bsums[i];
#pragma unroll
    for (int off = 32; off > 0; off >>= 1)
        s += __shfl_down(s, off, 64);
    if ((tid & 63) == 0) wred[tid >> 6] = s;
    __syncthreads();
    if (tid == 0)
        out[0] = (wred[0] + wred[1] + wred[2] + wred[3]) * (1.0f / (float)NPIX);
}

extern "C" void kernel_launch(void* const* d_in, const int* in_sizes, int n_in,
                              void* d_out, int out_size, void* d_ws, size_t ws_size,
                              hipStream_t stream) {
    const float* yp = (const float*)d_in[0];
    const float* yt = (const float*)d_in[1];
    float* out = (float*)d_out;

    float* bsums = (float*)d_ws;   // 4 KB of workspace
    sobel_loss_kernel<<<NB_MAIN, 256, 0, stream>>>(yp, yt, bsums);
    reduce_final<<<1, 256, 0, stream>>>(bsums, out);
}